// Round 1
// baseline (125.928 us; speedup 1.0000x reference)
//
#include <hip/hip_runtime.h>
#include <math.h>

// TopDownHTMM: C=32 states, 4-ary tree depth 7, N=21845 nodes, M=256 symbols.
// Scalar fp32 output = Pi_lh + A_lh + B_lh.
//
// Node layout (complete tree): level l in [0,7], nodes OFF[l]..OFF[l+1]-1,
// parent(n) = (n-1)>>2, pos(n) = (n-1)&3.
//
// Workspace (float) layout — ~11.3 MB total:
#define NNODES 21845
#define NF (NNODES * 32)

enum : int {
  W_PRIOR = 0,            // [N][32]
  W_BETA  = NF,           // [N][32]
  W_TBETA = 2 * NF,       // [N][32] (children only)
  W_EPS   = 3 * NF,       // [N][32]
  W_AST   = 4 * NF,       // AsT[e][j][i] = smA[i][j][e]   (4096)
  W_AS    = W_AST + 4096, // As [e][i][j] = smA[i][j][e]   (4096)
  W_ALT   = W_AS + 4096,  // AlT[e][j][i] = log smA[i][j][e] (4096)
  W_SPI   = W_ALT + 4096, // smPi (32)
  W_LPI   = W_SPI + 32,   // log smPi (32)
  W_SBT   = W_LPI + 32,   // smB^T [s][i] (8192)
  W_LBT   = W_SBT + 8192, // log smB^T [s][i] (8192)
  W_PART  = W_LBT + 8192, // per-block lh partials (<= 2731)
};

__device__ inline float hsum32(float v) {
#pragma unroll
  for (int m = 16; m >= 1; m >>= 1) v += __shfl_xor(v, m, 32);
  return v;
}

// grid 33 x 256. blocks 0..31: softmax rows of B. block 32: smA + smPi.
__global__ void k_precompute(const float* __restrict__ A, const float* __restrict__ Bm,
                             const float* __restrict__ Pi, float* __restrict__ W) {
  __shared__ float sh[256];
  int tid = threadIdx.x;
  int b = blockIdx.x;
  if (b < 32) {
    int r = b, s = tid;
    float x = Bm[r * 256 + s];
    sh[tid] = x; __syncthreads();
    for (int off = 128; off >= 1; off >>= 1) {
      if (tid < off) sh[tid] = fmaxf(sh[tid], sh[tid + off]);
      __syncthreads();
    }
    float m = sh[0]; __syncthreads();
    float e = expf(x - m);
    sh[tid] = e; __syncthreads();
    for (int off = 128; off >= 1; off >>= 1) {
      if (tid < off) sh[tid] += sh[tid + off];
      __syncthreads();
    }
    float sum = sh[0];
    W[W_SBT + s * 32 + r] = e / sum;
    W[W_LBT + s * 32 + r] = (x - m) - logf(sum);
  } else {
    if (tid < 128) {           // one (e,j) column of A, softmax over i
      int e = tid >> 5, j = tid & 31;
      float m = -1e30f;
      for (int i = 0; i < 32; i++) m = fmaxf(m, A[(i * 32 + j) * 4 + e]);
      float s = 0.f;
      for (int i = 0; i < 32; i++) s += expf(A[(i * 32 + j) * 4 + e] - m);
      float ls = logf(s);
      for (int i = 0; i < 32; i++) {
        float a = A[(i * 32 + j) * 4 + e];
        float sm = expf(a - m) / s;
        W[W_AST + e * 1024 + j * 32 + i] = sm;
        W[W_AS  + e * 1024 + i * 32 + j] = sm;
        W[W_ALT + e * 1024 + j * 32 + i] = (a - m) - ls;
      }
    } else if (tid == 128) {   // smPi
      float m = -1e30f;
      for (int i = 0; i < 32; i++) m = fmaxf(m, Pi[i]);
      float s = 0.f;
      for (int i = 0; i < 32; i++) s += expf(Pi[i] - m);
      float ls = logf(s);
      for (int i = 0; i < 32; i++) {
        W[W_SPI + i] = expf(Pi[i] - m) / s;
        W[W_LPI + i] = (Pi[i] - m) - ls;
      }
    }
  }
}

// 1 x 32: prior/beta at root.
__global__ void k_init(const int* __restrict__ labels, float* __restrict__ W) {
  int i = threadIdx.x;
  float pr = W[W_SPI + i];
  W[W_PRIOR + i] = pr;
  W[W_BETA + i] = pr * W[W_SBT + labels[0] * 32 + i];
}

// Downward prior sweep, one level. lane=i, 8 nodes/block.
__global__ __launch_bounds__(256) void k_down(const int* __restrict__ labels,
                                              float* __restrict__ W,
                                              int nStart, int cnt, int leaf) {
  __shared__ float sAT[4096];
  int tid = threadIdx.x;
  for (int k = tid; k < 4096; k += 256) sAT[k] = W[W_AST + k];
  __syncthreads();
  int idx = blockIdx.x * 8 + (tid >> 5);
  int lane = tid & 31;
  if (idx >= cnt) return;
  int n = nStart + idx;
  int pa = (n - 1) >> 2, e = (n - 1) & 3;
  float pj = W[W_PRIOR + pa * 32 + lane];
  float acc = 0.f;
#pragma unroll
  for (int j = 0; j < 32; j++)
    acc += sAT[e * 1024 + j * 32 + lane] * __shfl(pj, j, 32);
  W[W_PRIOR + n * 32 + lane] = acc;
  float bv = acc * W[W_SBT + labels[n] * 32 + lane];
  if (leaf) { float s = hsum32(bv); bv /= s; }
  W[W_BETA + n * 32 + lane] = bv;
}

// Upward sweep, one level: lane=j, one PARENT per 32-lane group (4 children each).
__global__ __launch_bounds__(256) void k_up(float* __restrict__ W, int pStart, int pcnt) {
  __shared__ float sA[4096];
  int tid = threadIdx.x;
  for (int k = tid; k < 4096; k += 256) sA[k] = W[W_AS + k];
  __syncthreads();
  int idx = blockIdx.x * 8 + (tid >> 5);
  int j = tid & 31;
  if (idx >= pcnt) return;
  int pa = pStart + idx;
  float ppj = W[W_PRIOR + pa * 32 + j];
  float prod = 1.f;
#pragma unroll
  for (int c = 0; c < 4; c++) {
    int n = 4 * pa + 1 + c;            // pos(n) == c
    float bc = W[W_BETA + n * 32 + j];
    float acc = 0.f;
#pragma unroll
    for (int i = 0; i < 32; i++)
      acc += sA[c * 1024 + i * 32 + j] * __shfl(bc, i, 32);
    float buv = acc / ppj;
    W[W_TBETA + n * 32 + j] = buv;
    prod *= buv;
  }
  float bnew = W[W_BETA + pa * 32 + j] * prod;
  float s = hsum32(bnew);
  bnew /= s;
  W[W_BETA + pa * 32 + j] = bnew;
  if (pa == 0) W[W_EPS + j] = bnew;    // eps[root] = beta[root]
}

// Downward eps sweep, one level. lane=i. Fuses t_eps row-sums + A_lh + B_lh.
__global__ __launch_bounds__(256) void k_eps(const int* __restrict__ labels,
                                             float* __restrict__ W,
                                             int nStart, int cnt, int partBase) {
  __shared__ float sAT[4096];
  __shared__ float sLT[4096];
  __shared__ float sred[8];
  int tid = threadIdx.x;
  for (int k = tid; k < 4096; k += 256) { sAT[k] = W[W_AST + k]; sLT[k] = W[W_ALT + k]; }
  __syncthreads();
  int idx = blockIdx.x * 8 + (tid >> 5);
  int i = tid & 31;
  float part = 0.f;
  if (idx < cnt) {
    int n = nStart + idx;
    int pa = (n - 1) >> 2, e = (n - 1) & 3;
    float ratio = W[W_BETA + n * 32 + i] / W[W_PRIOR + n * 32 + i];
    float q = W[W_EPS + pa * 32 + i] / W[W_TBETA + n * 32 + i]; // q[j] held by lane j
    float num = 0.f, alh = 0.f;
#pragma unroll
    for (int j = 0; j < 32; j++) {
      float s = __shfl(q, j, 32);
      float te = ratio * sAT[e * 1024 + j * 32 + i] * s;  // t_eps[i][j]
      num += te;
      alh += te * sLT[e * 1024 + j * 32 + i];
    }
    float den = hsum32(num);
    float epsi = num / den;
    W[W_EPS + n * 32 + i] = epsi;
    part = alh + epsi * W[W_LBT + labels[n] * 32 + i];
  }
  float hs = hsum32(part);
  if ((tid & 31) == 0) sred[tid >> 5] = hs;
  __syncthreads();
  if (tid == 0) {
    float t = 0.f;
#pragma unroll
    for (int w = 0; w < 8; w++) t += sred[w];
    W[W_PART + partBase + blockIdx.x] = t;
  }
}

// 1 x 256: sum partials + root Pi_lh + root B_lh term.
__global__ void k_final(const int* __restrict__ labels, const float* __restrict__ W,
                        float* __restrict__ out, int nPart) {
  __shared__ float sh[256];
  int tid = threadIdx.x;
  float a = 0.f;
  for (int k = tid; k < nPart; k += 256) a += W[W_PART + k];
  if (tid < 32) {
    float e0 = W[W_EPS + tid];
    a += e0 * (W[W_LPI + tid] + W[W_LBT + labels[0] * 32 + tid]);
  }
  sh[tid] = a; __syncthreads();
  for (int off = 128; off >= 1; off >>= 1) {
    if (tid < off) sh[tid] += sh[tid + off];
    __syncthreads();
  }
  if (tid == 0) out[0] = sh[0];
}

extern "C" void kernel_launch(void* const* d_in, const int* in_sizes, int n_in,
                              void* d_out, int out_size, void* d_ws, size_t ws_size,
                              hipStream_t stream) {
  const float* A  = (const float*)d_in[0];
  const float* Bm = (const float*)d_in[1];
  const float* Pi = (const float*)d_in[2];
  // d_in[3]=edges, d_in[4]=pos are implied by the complete-tree structure.
  const int* labels = (const int*)d_in[5];
  float* W = (float*)d_ws;
  float* out = (float*)d_out;

  static const int OFF[9] = {0, 1, 5, 21, 85, 341, 1365, 5461, 21845};

  k_precompute<<<33, 256, 0, stream>>>(A, Bm, Pi, W);
  k_init<<<1, 32, 0, stream>>>(labels, W);

  // downward prior
  for (int l = 1; l <= 7; l++) {
    int cnt = OFF[l + 1] - OFF[l];
    int grid = (cnt + 7) / 8;
    k_down<<<grid, 256, 0, stream>>>(labels, W, OFF[l], cnt, l == 7 ? 1 : 0);
  }
  // upward beta / t_beta
  for (int l = 7; l >= 1; l--) {
    int pcnt = (OFF[l + 1] - OFF[l]) / 4;
    int grid = (pcnt + 7) / 8;
    k_up<<<grid, 256, 0, stream>>>(W, OFF[l - 1], pcnt);
  }
  // downward eps + fused likelihood partials
  int partBase = 0;
  for (int l = 1; l <= 7; l++) {
    int cnt = OFF[l + 1] - OFF[l];
    int grid = (cnt + 7) / 8;
    k_eps<<<grid, 256, 0, stream>>>(labels, W, OFF[l], cnt, partBase);
    partBase += grid;
  }
  k_final<<<1, 256, 0, stream>>>(labels, W, out, partBase);
}